// Round 16
// baseline (688.218 us; speedup 1.0000x reference)
//
#include <hip/hip_runtime.h>
#include <hip/hip_bf16.h>
#include <cstdint>

#define B_ 8
#define C_ 192
#define N_ 3136
#define K_ 9
#define OC_ 384
#define QT_ 98            // q-tiles per batch (32 q each)
#define MS_ 4             // m-split stride over the 49 m-tiles (64 m each)
#define NT_ 49            // m-tiles (3136/64 exact)
#define QSZ 12288         // Q region: 6 kc x 32 node x 64 f16 = 24KB

typedef unsigned int u32;
typedef _Float16 f16x8 __attribute__((ext_vector_type(8)));
typedef __fp16 h2 __attribute__((ext_vector_type(2)));
typedef float f32x4 __attribute__((ext_vector_type(4)));

#define GLD(g, s) __builtin_amdgcn_global_load_lds( \
    (const __attribute__((address_space(1))) void*)(g), \
    (__attribute__((address_space(3))) void*)(s), 16, 0, 0)

#define WAITV2 asm volatile("s_waitcnt vmcnt(2)" ::: "memory")
#define WAITV0 asm volatile("s_waitcnt vmcnt(0)" ::: "memory")

// if-converted sorted bubble insert (static indexing, strict < keeps earlier m)
#define INS(LV, LI, dd, mm) { \
    float cv = (dd); int ci = (mm); \
    _Pragma("unroll") \
    for (int r_ = 0; r_ < 9; ++r_) { \
        bool sw_ = cv < LV[r_]; \
        float tv_ = LV[r_]; int ti_ = LI[r_]; \
        LV[r_] = sw_ ? cv : tv_;  LI[r_] = sw_ ? ci : ti_; \
        cv = sw_ ? tv_ : cv;      ci = sw_ ? ti_ : ci; \
    } }

// ---------------- Kernel A: normalize + f16 hi/lo split + transpose + sq ----------------
__global__ __launch_bounds__(64) void prep_k(const float* __restrict__ x,
                                             _Float16* __restrict__ pHL,
                                             float* __restrict__ xT,
                                             float* __restrict__ sq) {
    int g = blockIdx.x * 64 + threadIdx.x;       // 392*64 = 25088 exact
    int b = g / N_, n = g % N_;
    const float* xb = x + (size_t)b * C_ * N_ + n;
    float ss = 0.f;
    for (int c = 0; c < C_; ++c) { float v = xb[(size_t)c * N_]; ss = fmaf(v, v, ss); }
    float den = fmaxf(sqrtf(ss), 1e-12f);
    float* xrow = xT + (size_t)g * C_;
    _Float16* hrow = pHL + (size_t)g * 384;
    float s2 = 0.f;
    for (int c4 = 0; c4 < 48; ++c4) {
        float4 vv; float* pv = &vv.x;
        union { _Float16 f[4]; uint2 u; } uh, ul;
        #pragma unroll
        for (int j = 0; j < 4; ++j) {
            int c = 4 * c4 + j;
            float v = xb[(size_t)c * N_];
            float p = v / den;                    // IEEE div, matches np divide
            pv[j] = v;
            _Float16 h = (_Float16)p;            // rne
            uh.f[j] = h;
            ul.f[j] = (_Float16)(p - (float)h);  // residual
            s2 = fmaf(p, p, s2);                 // sq chain identical to passing rounds
        }
        *(float4*)&xrow[4 * c4] = vv;
        *(uint2*)&hrow[4 * c4] = uh.u;
        *(uint2*)&hrow[192 + 4 * c4] = ul.u;
    }
    sq[g] = s2;
}

// ---------------- Kernel B: MFMA distance GEMM, 48KB LDS -> 3 blocks/CU ----------------
// Block 32q x 64m-tile, 4 waves; wave tile 32q x 16m (2 mfma tiles x 3 products).
// Q resident 24KB; M dbuf 2x8KB wave-local (rows [16w,16w+16), 2 GLD/kc, WAITV2,
// no barriers in kc-loop). dist[64m][32q] = SEPARATE 8KB region (no aliasing).
// Barrier discipline identical to R14 (proven): post-kc / post-write / post-scan.
__global__ __launch_bounds__(256, 4) void knn_k(const _Float16* __restrict__ pHL,
                                                const float* __restrict__ sq,
                                                float* __restrict__ pkv,
                                                int* __restrict__ pki) {
    __shared__ _Float16 sh[24576];                // 48KB: Q 0..12287 | M0 12288 | M1 16384 | dist 20480
    float* dist = (float*)(sh + 20480);           // 8KB, dedicated (never staged into)
    const int tid = threadIdx.x;
    const int w = tid >> 6, l = tid & 63;
    const int lr = l & 15, lg = l >> 4;
    const int bid = blockIdx.x;
    const int b = bid & 7;                        // XCD-affinity: one batch per XCD
    const int r2_ = bid >> 3;                     // 0..391
    const int qt = r2_ >> 2, s4 = r2_ & 3;
    const int q0 = qt * 32;
    const char* hbB = (const char*)(pHL + (size_t)b * N_ * 384);
    const float* sqb = sq + b * N_;

    const int nl = l >> 3, sl = l & 7, ol = sl ^ nl;
    const size_t lane_src = (size_t)nl * 768 + (size_t)(ol >> 2) * 384 + (size_t)(ol & 3) * 16;
    const int slot_h = (lg ^ (lr & 7)) * 8;
    const int slot_l = ((4 | lg) ^ (lr & 7)) * 8;

    float sqq[2][4];
    #pragma unroll
    for (int qs = 0; qs < 2; ++qs)
        #pragma unroll
        for (int r = 0; r < 4; ++r) sqq[qs][r] = sqb[q0 + 16 * qs + 4 * lg + r];

    float lv[9]; int li[9];
    #pragma unroll
    for (int r = 0; r < 9; ++r) { lv[r] = INFINITY; li[r] = 0x7fffffff; }

    auto stageM = [&](int mt_, int kc_, int buf) { // wave-local rows [16w, 16w+16)
        size_t mb = (size_t)(mt_ * 64 + w * 16) * 768 + (size_t)kc_ * 64;
        _Float16* md = sh + QSZ + buf * 4096 + w * 1024;
        GLD(hbB + mb + lane_src, md);
        GLD(hbB + mb + 6144 + lane_src, md + 512);
    };

    // ---- stage Q once: [6 kc][32 node][64 f16]; wave w rows [8w,8w+8) ----
    #pragma unroll
    for (int kc = 0; kc < 6; ++kc) {
        size_t qb = (size_t)(q0 + 8 * w) * 768 + (size_t)kc * 64;
        GLD(hbB + qb + lane_src, sh + kc * 2048 + w * 512);
    }
    __syncthreads();                              // Q visible (drains vmem)

    for (int mt = s4; mt < NT_; mt += MS_) {
        const int m0 = mt * 64;
        stageM(mt, 0, 0);                         // tile-start stage
        f32x4 acc[2];
        acc[0] = (f32x4)0.f; acc[1] = (f32x4)0.f;

        #pragma unroll
        for (int kc = 0; kc < 6; ++kc) {          // NO barriers in this loop (wave-local M)
            if (kc < 5) {
                stageM(mt, kc + 1, (kc + 1) & 1); // issue next chunk
                WAITV2;                           // oldest 2 = stage(kc) complete
            } else {
                WAITV0;
            }
            const _Float16* Qb = sh + kc * 2048;
            const _Float16* mrow = sh + QSZ + (kc & 1) * 4096 + (16 * w + lr) * 64;
            f16x8 bh = *(const f16x8*)(mrow + slot_h);
            f16x8 bl = *(const f16x8*)(mrow + slot_l);
            #pragma unroll
            for (int qs = 0; qs < 2; ++qs) {
                const _Float16* qrow = Qb + (16 * qs + lr) * 64;
                f16x8 ah = *(const f16x8*)(qrow + slot_h);
                f16x8 al = *(const f16x8*)(qrow + slot_l);
                acc[qs] = __builtin_amdgcn_mfma_f32_16x16x32_f16(al, bh, acc[qs], 0, 0, 0);
                acc[qs] = __builtin_amdgcn_mfma_f32_16x16x32_f16(ah, bl, acc[qs], 0, 0, 0);
                acc[qs] = __builtin_amdgcn_mfma_f32_16x16x32_f16(ah, bh, acc[qs], 0, 0, 0);
            }
        }
        __syncthreads();                          // all waves done with M bufs (R14 discipline)

        // ---- epilogue: dist[64 m][32 q], dedicated region ----
        const float sqm = sqb[m0 + 16 * w + lr];
        {
            const int col = 16 * w + lr;
            #pragma unroll
            for (int qs = 0; qs < 2; ++qs) {
                int g2 = 4 * qs + lg;             // q-granule 0..7
                int gsw = (g2 ^ (col & 7)) << 2;  // XOR swizzle (bijective per col)
                float4 v;
                v.x = (sqq[qs][0] - 2.0f * acc[qs][0]) + sqm;
                v.y = (sqq[qs][1] - 2.0f * acc[qs][1]) + sqm;
                v.z = (sqq[qs][2] - 2.0f * acc[qs][2]) + sqm;
                v.w = (sqq[qs][3] - 2.0f * acc[qs][3]) + sqm;
                *(float4*)&dist[col * 32 + gsw] = v;
            }
        }
        __syncthreads();                          // dist visible to all scanners
        // ---- scan: thread (q = tid&31, seg = tid>>5) scans cols seg*8..seg*8+7 ----
        const int q = tid & 31, seg = tid >> 5;
        #pragma unroll
        for (int jj = 0; jj < 8; ++jj) {
            int col = seg * 8 + jj;
            int m = m0 + col;                     // always < N_ (49*64 exact)
            float d = dist[col * 32 + (((q >> 2) ^ (col & 7)) << 2) + (q & 3)];
            INS(lv, li, d, m)
        }
        __syncthreads();                          // scans done before next tile's stage
    }
    // ---- merge the 8 seg-lists per query (stable: val asc, idx asc) ----
    float* Lv = (float*)sh;                       // Q region dead
    int*   Li = (int*)sh + 2304;
    #pragma unroll
    for (int r = 0; r < 9; ++r) { Lv[tid * 9 + r] = lv[r]; Li[tid * 9 + r] = li[r]; }
    __syncthreads();
    if (tid < 32) {
        size_t base = ((size_t)((b * QT_ + qt) * MS_ + s4) * 32 + tid) * 9;
        for (int r = 0; r < K_; ++r) {
            float best = INFINITY; int bidx = 0x7fffffff; int bp = 0;
            for (int s = 0; s < 8; ++s) {
                int lb = (s * 32 + tid) * 9;
                for (int e = 0; e < 9; ++e) {
                    float v = Lv[lb + e]; int id = Li[lb + e];
                    if (v < best || (v == best && id < bidx)) { best = v; bidx = id; bp = lb + e; }
                }
            }
            pkv[base + r] = best;
            pki[base + r] = bidx;
            Lv[bp] = INFINITY;
        }
    }
}

// ---------------- Kernel B2: merge the 4 stride lists per query ----------------
__global__ __launch_bounds__(64) void merge_k(const float* __restrict__ pkv,
                                              const int* __restrict__ pki,
                                              int* __restrict__ nn) {
    int g = blockIdx.x * 64 + threadIdx.x;        // 392*64 = 25088 exact
    int b = g / N_, n = g % N_;
    int qt = n >> 5, q = n & 31;
    float v[MS_ * 9]; int id[MS_ * 9];
    #pragma unroll
    for (int s = 0; s < MS_; ++s) {
        size_t base = ((size_t)((b * QT_ + qt) * MS_ + s) * 32 + q) * 9;
        #pragma unroll
        for (int e = 0; e < 9; ++e) { v[s * 9 + e] = pkv[base + e]; id[s * 9 + e] = pki[base + e]; }
    }
    int* onn = nn + (size_t)g * K_;
    for (int r = 0; r < K_; ++r) {
        float best = INFINITY; int bidx = 0x7fffffff; int bp = 0;
        #pragma unroll
        for (int e = 0; e < MS_ * 9; ++e) {
            if (v[e] < best || (v[e] == best && id[e] < bidx)) { best = v[e]; bidx = id[e]; bp = e; }
        }
        onn[r] = bidx;
        v[bp] = INFINITY;
    }
}

// ---------------- Kernel C: channels 0..191, 8 oranges x 24 out-ch (grid 784) ----------------
__global__ __launch_bounds__(256) void convi_k(const float* __restrict__ x,
                                               const float* __restrict__ W,
                                               const float* __restrict__ bias,
                                               float* __restrict__ out) {
    __shared__ float Ws[24 * 96];
    const int orange = blockIdx.x & 7;
    const int nb = blockIdx.x >> 3;
    const int tid = threadIdx.x;
    const int g = nb * 256 + tid;
    const int b = g / N_, n = g % N_;
    const int o0 = orange * 24;
    const int cb = (o0 >= 96) ? 96 : 0;
    for (int i = 0; i < 9; ++i) {
        int e = tid + i * 256;
        Ws[e] = W[o0 * 96 + e];
    }
    __syncthreads();
    const float* xb = x + ((size_t)b * C_ + cb) * N_ + n;
    float xi[96];
    #pragma unroll
    for (int c = 0; c < 96; ++c) xi[c] = xb[(size_t)c * N_];
    float* ob = out + ((size_t)b * OC_ + o0) * N_ + n;
    for (int o = 0; o < 24; ++o) {
        float a = bias[o0 + o];
        #pragma unroll
        for (int c4 = 0; c4 < 24; ++c4) {
            float4 w4 = *(const float4*)&Ws[o * 96 + 4 * c4];
            a = fmaf(w4.x, xi[4*c4+0], a);
            a = fmaf(w4.y, xi[4*c4+1], a);
            a = fmaf(w4.z, xi[4*c4+2], a);
            a = fmaf(w4.w, xi[4*c4+3], a);
        }
        ob[(size_t)o * N_] = fmaxf(a, 0.f);
    }
}

// ---------------- Kernel D: channels 192..383 via v_dot2_f32_f16 ----------------
__global__ __launch_bounds__(256) void convd_k(const float* __restrict__ xT,
                                               const int* __restrict__ nn,
                                               const float* __restrict__ W,
                                               const float* __restrict__ bias,
                                               float* __restrict__ out) {
    __shared__ _Float16 Wb[192 * 106];            // 40704 B
    __shared__ _Float16 dif[4][9 * 192];          // [wave][k][c], 13824 B
    const int tid = threadIdx.x;
    const int w = tid >> 6, l = tid & 63;
    const int b = blockIdx.x / 196;
    const int n0 = (blockIdx.x % 196) * 16;
    const bool hi2 = (l >= 32);                   // a1 group select

    for (int i = 0; i < 72; ++i) {
        int e = tid + i * 256;                    // 18432 = 192*96
        int row = e / 96, j = e % 96;
        Wb[row * 106 + j] = (_Float16)W[(192 + row) * 96 + j];
    }
    float bo[3];
    #pragma unroll
    for (int oi = 0; oi < 3; ++oi) bo[oi] = bias[192 + l + 64 * oi];
    __syncthreads();

    _Float16* df = dif[w];
    const float* xTb = xT + (size_t)b * N_ * C_;
    float mx0[4], mx1[4], mx2[4];

    #pragma unroll
    for (int r = 0; r < 4; ++r) {
        const int n = n0 + 4 * w + r;
        const float* xin = xTb + (size_t)n * C_;
        float xi0 = xin[l], xi1 = xin[l + 64], xi2 = xin[l + 128];
        const int* nb2 = nn + ((size_t)b * N_ + n) * K_;
        __syncthreads();                          // WAR vs previous round's reads
        #pragma unroll
        for (int k = 0; k < K_; ++k) {
            int idx = nb2[k];
            const float* xj = xTb + (size_t)idx * C_;
            df[k * 192 + l]       = (_Float16)(xj[l]       - xi0);
            df[k * 192 + l + 64]  = (_Float16)(xj[l + 64]  - xi1);
            df[k * 192 + l + 128] = (_Float16)(xj[l + 128] - xi2);
        }
        __syncthreads();                          // writes visible
        float a0[9], a1[9], a2[9];
        #pragma unroll
        for (int k = 0; k < 9; ++k) { a0[k] = 0.f; a1[k] = 0.f; a2[k] = 0.f; }

        for (int jj = 0; jj < 12; ++jj) {
            union U { uint4 u; h2 p[4]; };
            U w0u, w1u, w2u;
            w0u.u = *(const uint4*)(Wb + (size_t)l * 106 + jj * 8);
            w1u.u = *(const uint4*)(Wb + (size_t)(l + 64) * 106 + jj * 8);
            w2u.u = *(const uint4*)(Wb + (size_t)(l + 128) * 106 + jj * 8);
            #pragma unroll
            for (int k = 0; k < 9; ++k) {
                const _Float16* dk = df + k * 192 + jj * 8;
                U dA, dB, dC;
                dA.u = *(const uint4*)(dk);            // c = 8jj..    (broadcast)
                dB.u = *(const uint4*)(dk + 96);       // c = 96+8jj.. (broadcast)
                dC.u.x = hi2 ? dB.u.x : dA.u.x;        // a1 operand: lane-group select
                dC.u.y = hi2 ? dB.u.y : dA.u.y;
                dC.u.z = hi2 ? dB.u.z : dA.u.z;
                dC.u.w = hi2 ? dB.u.w : dA.u.w;
                #pragma unroll
                for (int p = 0; p < 4; ++p) {          // pairs j-ascending
                    a0[k] = __builtin_amdgcn_fdot2(w0u.p[p], dA.p[p], a0[k], false);
                    a1[k] = __builtin_amdgcn_fdot2(w1u.p[p], dC.p[p], a1[k], false);
                    a2[k] = __builtin_amdgcn_fdot2(w2u.p[p], dB.p[p], a2[k], false);
                }
            }
        }
        float m0 = a0[0] + bo[0], m1 = a1[0] + bo[1], m2 = a2[0] + bo[2];
        #pragma unroll
        for (int k = 1; k < 9; ++k) {
            m0 = fmaxf(m0, a0[k] + bo[0]);
            m1 = fmaxf(m1, a1[k] + bo[1]);
            m2 = fmaxf(m2, a2[k] + bo[2]);
        }
        mx0[r] = fmaxf(m0, 0.f); mx1[r] = fmaxf(m1, 0.f); mx2[r] = fmaxf(m2, 0.f);
    }
    float* ob = out + ((size_t)b * OC_ + 192) * N_ + n0 + 4 * w;
    *(float4*)&ob[(size_t)(l)       * N_] = make_float4(mx0[0], mx0[1], mx0[2], mx0[3]);
    *(float4*)&ob[(size_t)(l + 64)  * N_] = make_float4(mx1[0], mx1[1], mx1[2], mx1[3]);
    *(float4*)&ob[(size_t)(l + 128) * N_] = make_float4(mx2[0], mx2[1], mx2[2], mx2[3]);
}

extern "C" void kernel_launch(void* const* d_in, const int* in_sizes, int n_in,
                              void* d_out, int out_size, void* d_ws, size_t ws_size,
                              hipStream_t stream) {
    (void)in_sizes; (void)n_in; (void)out_size; (void)ws_size;
    const float* x    = (const float*)d_in[0];
    const float* W    = (const float*)d_in[1];
    const float* bias = (const float*)d_in[2];
    float* out = (float*)d_out;

    _Float16* pHL = (_Float16*)d_ws;                       // 8*3136*384 f16 (hi|lo, node-major)
    float* xT   = (float*)(pHL + (size_t)B_ * N_ * 384);   // 8*3136*192 f32 raw
    float* sq   = xT + (size_t)B_ * N_ * C_;               // 8*3136 f32
    int*   nn   = (int*)(sq + (size_t)B_ * N_);            // 8*3136*9 i32
    float* pkv  = (float*)(nn + (size_t)B_ * N_ * K_);     // partial vals
    int*   pki  = (int*)(pkv + (size_t)B_ * QT_ * MS_ * 32 * 9);

    hipLaunchKernelGGL(prep_k,  dim3(392),  dim3(64),  0, stream, x, pHL, xT, sq);
    hipLaunchKernelGGL(knn_k,   dim3(B_ * QT_ * MS_), dim3(256), 0, stream, pHL, sq, pkv, pki);
    hipLaunchKernelGGL(merge_k, dim3(392),  dim3(64),  0, stream, pkv, pki, nn);
    hipLaunchKernelGGL(convi_k, dim3(784),  dim3(256), 0, stream, x, W, bias, out);
    hipLaunchKernelGGL(convd_k, dim3(1568), dim3(256), 0, stream, xT, nn, W, bias, out);
}

// Round 22
// 672.159 us; speedup vs baseline: 1.0239x; 1.0239x over previous
//
#include <hip/hip_runtime.h>
#include <hip/hip_bf16.h>
#include <cstdint>

#define B_ 8
#define C_ 192
#define N_ 3136
#define K_ 9
#define OC_ 384
#define QT_ 49            // q-tiles per batch (64 q each)
#define MS_ 4             // m-split stride over the 49 m-tiles (64 m each)
#define NT_ 49            // m-tiles (3136/64 exact, no tail)
#define QSZ 24576         // Q region: 6 kc x 64 node x 64 f16 = 48KB

typedef unsigned int u32;
typedef _Float16 f16x8 __attribute__((ext_vector_type(8)));
typedef __fp16 h2 __attribute__((ext_vector_type(2)));
typedef float f32x4 __attribute__((ext_vector_type(4)));

#define GLD(g, s) __builtin_amdgcn_global_load_lds( \
    (const __attribute__((address_space(1))) void*)(g), \
    (__attribute__((address_space(3))) void*)(s), 16, 0, 0)

#define WAITV2 asm volatile("s_waitcnt vmcnt(2)" ::: "memory")
#define WAITV0 asm volatile("s_waitcnt vmcnt(0)" ::: "memory")

// if-converted sorted bubble insert (static indexing, strict < keeps earlier m)
#define INS(LV, LI, dd, mm) { \
    float cv = (dd); int ci = (mm); \
    _Pragma("unroll") \
    for (int r_ = 0; r_ < 9; ++r_) { \
        bool sw_ = cv < LV[r_]; \
        float tv_ = LV[r_]; int ti_ = LI[r_]; \
        LV[r_] = sw_ ? cv : tv_;  LI[r_] = sw_ ? ci : ti_; \
        cv = sw_ ? tv_ : cv;      ci = sw_ ? ti_ : ci; \
    } }

// ---------------- Kernel A: normalize + f16 hi/lo split + transpose + sq ----------------
__global__ __launch_bounds__(64) void prep_k(const float* __restrict__ x,
                                             _Float16* __restrict__ pHL,
                                             float* __restrict__ xT,
                                             float* __restrict__ sq) {
    int g = blockIdx.x * 64 + threadIdx.x;       // 392*64 = 25088 exact
    int b = g / N_, n = g % N_;
    const float* xb = x + (size_t)b * C_ * N_ + n;
    float ss = 0.f;
    for (int c = 0; c < C_; ++c) { float v = xb[(size_t)c * N_]; ss = fmaf(v, v, ss); }
    float den = fmaxf(sqrtf(ss), 1e-12f);
    float* xrow = xT + (size_t)g * C_;
    _Float16* hrow = pHL + (size_t)g * 384;
    float s2 = 0.f;
    for (int c4 = 0; c4 < 48; ++c4) {
        float4 vv; float* pv = &vv.x;
        union { _Float16 f[4]; uint2 u; } uh, ul;
        #pragma unroll
        for (int j = 0; j < 4; ++j) {
            int c = 4 * c4 + j;
            float v = xb[(size_t)c * N_];
            float p = v / den;                    // IEEE div, matches np divide
            pv[j] = v;
            _Float16 h = (_Float16)p;            // rne
            uh.f[j] = h;
            ul.f[j] = (_Float16)(p - (float)h);  // residual
            s2 = fmaf(p, p, s2);                 // sq chain identical to passing rounds
        }
        *(float4*)&xrow[4 * c4] = vv;
        *(uint2*)&hrow[4 * c4] = uh.u;
        *(uint2*)&hrow[192 + 4 * c4] = ul.u;
    }
    sq[g] = s2;
}

// ---------------- Kernel B: MFMA distance GEMM (R14 structure + DEDICATED dist) ----------------
// Block 64q x 64m-tile, 4 waves; wave tile 64q x 16m. Q resident 48KB; M dbuf
// 2x8KB wave-local (rows [16w,16w+16), 2 GLD/kc, WAITV2, no barriers in kc-loop).
// dist[64m][64q] = DEDICATED 16KB region (never written by global_load_lds) --
// removes the latent alias hazard implicated in the R15/R21 failures.
__global__ __launch_bounds__(256, 2) void knn_k(const _Float16* __restrict__ pHL,
                                                const float* __restrict__ sq,
                                                float* __restrict__ pkv,
                                                int* __restrict__ pki) {
    __shared__ _Float16 sh[40960];                // 80KB: Q 0..24575 | M0 24576 | M1 28672 | dist 32768
    float* dist = (float*)(sh + 32768);           // 16KB dedicated
    const int tid = threadIdx.x;
    const int w = tid >> 6, l = tid & 63;
    const int lr = l & 15, lg = l >> 4;
    const int bid = blockIdx.x;
    const int b = bid & 7;                        // XCD-affinity: one batch per XCD
    const int r2_ = bid >> 3;                     // 0..195
    const int qt = r2_ >> 2, s4 = r2_ & 3;
    const int q0 = qt * 64;
    const char* hbB = (const char*)(pHL + (size_t)b * N_ * 384);
    const float* sqb = sq + b * N_;

    const int nl = l >> 3, sl = l & 7, ol = sl ^ nl;
    const size_t lane_src = (size_t)nl * 768 + (size_t)(ol >> 2) * 384 + (size_t)(ol & 3) * 16;
    const int slot_h = (lg ^ (lr & 7)) * 8;
    const int slot_l = ((4 | lg) ^ (lr & 7)) * 8;

    float sqq[4][4];
    #pragma unroll
    for (int qs = 0; qs < 4; ++qs)
        #pragma unroll
        for (int r = 0; r < 4; ++r) sqq[qs][r] = sqb[q0 + 16 * qs + 4 * lg + r];

    float lvA[9], lvB[9]; int liA[9], liB[9];
    #pragma unroll
    for (int r = 0; r < 9; ++r) {
        lvA[r] = INFINITY; liA[r] = 0x7fffffff;
        lvB[r] = INFINITY; liB[r] = 0x7fffffff;
    }

    auto stageM = [&](int mt_, int kc_, int buf) { // wave-local rows [16w, 16w+16)
        size_t mb = (size_t)(mt_ * 64 + w * 16) * 768 + (size_t)kc_ * 64;
        _Float16* md = sh + QSZ + buf * 4096 + w * 1024;
        GLD(hbB + mb + lane_src, md);
        GLD(hbB + mb + 6144 + lane_src, md + 512);
    };

    // ---- stage Q once: [6 kc][64 node][64 f16]; wave w rows [16w,16w+16) ----
    #pragma unroll
    for (int kc = 0; kc < 6; ++kc) {
        size_t qb = (size_t)(q0 + w * 16) * 768 + (size_t)kc * 64;
        _Float16* qd = sh + kc * 4096 + w * 1024;
        GLD(hbB + qb + lane_src, qd);
        GLD(hbB + qb + 6144 + lane_src, qd + 512);
    }
    __syncthreads();                              // Q visible (drains vmem)

    for (int mt = s4; mt < NT_; mt += MS_) {
        const int m0 = mt * 64;
        stageM(mt, 0, 0);                         // tile-start stage (R14 pattern)
        f32x4 acc[4];
        #pragma unroll
        for (int qs = 0; qs < 4; ++qs) acc[qs] = (f32x4)0.f;

        #pragma unroll
        for (int kc = 0; kc < 6; ++kc) {          // NO barriers in this loop
            if (kc < 5) {
                stageM(mt, kc + 1, (kc + 1) & 1); // issue next chunk (same tile only)
                WAITV2;                           // oldest 2 = stage(kc) complete
            } else {
                WAITV0;
            }
            const _Float16* Qb = sh + kc * 4096;
            const _Float16* mrow = sh + QSZ + (kc & 1) * 4096 + (16 * w + lr) * 64;
            f16x8 bh = *(const f16x8*)(mrow + slot_h);
            f16x8 bl = *(const f16x8*)(mrow + slot_l);
            #pragma unroll
            for (int qs = 0; qs < 4; ++qs) {
                const _Float16* qrow = Qb + (16 * qs + lr) * 64;
                f16x8 ah = *(const f16x8*)(qrow + slot_h);
                f16x8 al = *(const f16x8*)(qrow + slot_l);
                acc[qs] = __builtin_amdgcn_mfma_f32_16x16x32_f16(al, bh, acc[qs], 0, 0, 0);
                acc[qs] = __builtin_amdgcn_mfma_f32_16x16x32_f16(ah, bl, acc[qs], 0, 0, 0);
                acc[qs] = __builtin_amdgcn_mfma_f32_16x16x32_f16(ah, bh, acc[qs], 0, 0, 0);
            }
        }
        __syncthreads();                          // all waves done reading M bufs

        // ---- epilogue: dist[64 m][64 q] (dedicated 16KB) ----
        const float sqm = sqb[m0 + 16 * w + lr];
        {
            const int col = 16 * w + lr;
            #pragma unroll
            for (int qs = 0; qs < 4; ++qs) {
                int gsw = ((4 * qs + lg) ^ lr) << 2;   // XOR-granule swizzle
                float4 v;
                v.x = (sqq[qs][0] - 2.0f * acc[qs][0]) + sqm;
                v.y = (sqq[qs][1] - 2.0f * acc[qs][1]) + sqm;
                v.z = (sqq[qs][2] - 2.0f * acc[qs][2]) + sqm;
                v.w = (sqq[qs][3] - 2.0f * acc[qs][3]) + sqm;
                *(float4*)&dist[col * 64 + gsw] = v;
            }
        }
        __syncthreads();
        // ---- scan: query = l, wave w owns cols [16w,16w+16) (R14 in-loop form) ----
        const int gq = l >> 2, qe = l & 3;
        #pragma unroll
        for (int jj = 0; jj < 16; ++jj) {
            int col = 16 * w + jj;
            int m = m0 + col;                     // always < N_ (49*64 = 3136 exact)
            float d = dist[col * 64 + ((gq ^ (col & 15)) << 2) + qe];
            if (jj & 1) { INS(lvB, liB, d, m) }
            else        { INS(lvA, liA, d, m) }
        }
        __syncthreads();                          // scans done before next tile's stage
    }
    // ---- merge the 8 lists per query (stable: val asc, idx asc) ----
    float* Lv = (float*)sh;
    int*   Li = (int*)sh + 4608;
    #pragma unroll
    for (int r = 0; r < 9; ++r) {
        Lv[(tid * 2 + 0) * 9 + r] = lvA[r]; Li[(tid * 2 + 0) * 9 + r] = liA[r];
        Lv[(tid * 2 + 1) * 9 + r] = lvB[r]; Li[(tid * 2 + 1) * 9 + r] = liB[r];
    }
    __syncthreads();
    if (tid < 64) {
        size_t base = ((size_t)((b * QT_ + qt) * MS_ + s4) * 64 + tid) * 9;
        for (int r = 0; r < K_; ++r) {
            float best = INFINITY; int bidx = 0x7fffffff; int bp = 0;
            for (int s = 0; s < 8; ++s) {
                int lb = (((s >> 1) * 64 + tid) * 2 + (s & 1)) * 9;
                for (int e = 0; e < 9; ++e) {
                    float v = Lv[lb + e]; int id = Li[lb + e];
                    if (v < best || (v == best && id < bidx)) { best = v; bidx = id; bp = lb + e; }
                }
            }
            pkv[base + r] = best;
            pki[base + r] = bidx;
            Lv[bp] = INFINITY;
        }
    }
}

// ---------------- Kernel B2: merge the 4 stride lists per query ----------------
__global__ __launch_bounds__(64) void merge_k(const float* __restrict__ pkv,
                                              const int* __restrict__ pki,
                                              int* __restrict__ nn) {
    int g = blockIdx.x * 64 + threadIdx.x;        // 392*64 = 25088 exact
    int b = g / N_, n = g % N_;
    int qt = n >> 6, q = n & 63;
    float v[MS_ * 9]; int id[MS_ * 9];
    #pragma unroll
    for (int s = 0; s < MS_; ++s) {
        size_t base = ((size_t)((b * QT_ + qt) * MS_ + s) * 64 + q) * 9;
        #pragma unroll
        for (int e = 0; e < 9; ++e) { v[s * 9 + e] = pkv[base + e]; id[s * 9 + e] = pki[base + e]; }
    }
    int* onn = nn + (size_t)g * K_;
    for (int r = 0; r < K_; ++r) {
        float best = INFINITY; int bidx = 0x7fffffff; int bp = 0;
        #pragma unroll
        for (int e = 0; e < MS_ * 9; ++e) {
            if (v[e] < best || (v[e] == best && id[e] < bidx)) { best = v[e]; bidx = id[e]; bp = e; }
        }
        onn[r] = bidx;
        v[bp] = INFINITY;
    }
}

// ---------------- Kernel C: channels 0..191, 8 oranges x 24 out-ch (grid 784) ----------------
__global__ __launch_bounds__(256) void convi_k(const float* __restrict__ x,
                                               const float* __restrict__ W,
                                               const float* __restrict__ bias,
                                               float* __restrict__ out) {
    __shared__ float Ws[24 * 96];
    const int orange = blockIdx.x & 7;
    const int nb = blockIdx.x >> 3;
    const int tid = threadIdx.x;
    const int g = nb * 256 + tid;
    const int b = g / N_, n = g % N_;
    const int o0 = orange * 24;
    const int cb = (o0 >= 96) ? 96 : 0;
    for (int i = 0; i < 9; ++i) {
        int e = tid + i * 256;
        Ws[e] = W[o0 * 96 + e];
    }
    __syncthreads();
    const float* xb = x + ((size_t)b * C_ + cb) * N_ + n;
    float xi[96];
    #pragma unroll
    for (int c = 0; c < 96; ++c) xi[c] = xb[(size_t)c * N_];
    float* ob = out + ((size_t)b * OC_ + o0) * N_ + n;
    for (int o = 0; o < 24; ++o) {
        float a = bias[o0 + o];
        #pragma unroll
        for (int c4 = 0; c4 < 24; ++c4) {
            float4 w4 = *(const float4*)&Ws[o * 96 + 4 * c4];
            a = fmaf(w4.x, xi[4*c4+0], a);
            a = fmaf(w4.y, xi[4*c4+1], a);
            a = fmaf(w4.z, xi[4*c4+2], a);
            a = fmaf(w4.w, xi[4*c4+3], a);
        }
        ob[(size_t)o * N_] = fmaxf(a, 0.f);
    }
}

// ---------------- Kernel D: channels 192..383 via v_dot2_f32_f16 (R14 verbatim) ----------------
__global__ __launch_bounds__(256) void convd_k(const float* __restrict__ xT,
                                               const int* __restrict__ nn,
                                               const float* __restrict__ W,
                                               const float* __restrict__ bias,
                                               float* __restrict__ out) {
    __shared__ _Float16 Wb[192 * 106];            // 40704 B
    __shared__ _Float16 dif[4][9 * 192];          // [wave][k][c], 13824 B
    const int tid = threadIdx.x;
    const int w = tid >> 6, l = tid & 63;
    const int b = blockIdx.x / 196;
    const int n0 = (blockIdx.x % 196) * 16;
    const bool hi2 = (l >= 32);                   // a1 group select

    for (int i = 0; i < 72; ++i) {
        int e = tid + i * 256;                    // 18432 = 192*96
        int row = e / 96, j = e % 96;
        Wb[row * 106 + j] = (_Float16)W[(192 + row) * 96 + j];
    }
    float bo[3];
    #pragma unroll
    for (int oi = 0; oi < 3; ++oi) bo[oi] = bias[192 + l + 64 * oi];
    __syncthreads();

    _Float16* df = dif[w];
    const float* xTb = xT + (size_t)b * N_ * C_;
    float mx0[4], mx1[4], mx2[4];

    #pragma unroll
    for (int r = 0; r < 4; ++r) {
        const int n = n0 + 4 * w + r;
        const float* xin = xTb + (size_t)n * C_;
        float xi0 = xin[l], xi1 = xin[l + 64], xi2 = xin[l + 128];
        const int* nb2 = nn + ((size_t)b * N_ + n) * K_;
        __syncthreads();                          // WAR vs previous round's reads
        #pragma unroll
        for (int k = 0; k < K_; ++k) {
            int idx = nb2[k];
            const float* xj = xTb + (size_t)idx * C_;
            df[k * 192 + l]       = (_Float16)(xj[l]       - xi0);
            df[k * 192 + l + 64]  = (_Float16)(xj[l + 64]  - xi1);
            df[k * 192 + l + 128] = (_Float16)(xj[l + 128] - xi2);
        }
        __syncthreads();                          // writes visible
        float a0[9], a1[9], a2[9];
        #pragma unroll
        for (int k = 0; k < 9; ++k) { a0[k] = 0.f; a1[k] = 0.f; a2[k] = 0.f; }

        for (int jj = 0; jj < 12; ++jj) {
            union U { uint4 u; h2 p[4]; };
            U w0u, w1u, w2u;
            w0u.u = *(const uint4*)(Wb + (size_t)l * 106 + jj * 8);
            w1u.u = *(const uint4*)(Wb + (size_t)(l + 64) * 106 + jj * 8);
            w2u.u = *(const uint4*)(Wb + (size_t)(l + 128) * 106 + jj * 8);
            #pragma unroll
            for (int k = 0; k < 9; ++k) {
                const _Float16* dk = df + k * 192 + jj * 8;
                U dA, dB, dC;
                dA.u = *(const uint4*)(dk);            // c = 8jj..    (broadcast)
                dB.u = *(const uint4*)(dk + 96);       // c = 96+8jj.. (broadcast)
                dC.u.x = hi2 ? dB.u.x : dA.u.x;        // a1 operand: lane-group select
                dC.u.y = hi2 ? dB.u.y : dA.u.y;
                dC.u.z = hi2 ? dB.u.z : dA.u.z;
                dC.u.w = hi2 ? dB.u.w : dA.u.w;
                #pragma unroll
                for (int p = 0; p < 4; ++p) {          // pairs j-ascending
                    a0[k] = __builtin_amdgcn_fdot2(w0u.p[p], dA.p[p], a0[k], false);
                    a1[k] = __builtin_amdgcn_fdot2(w1u.p[p], dC.p[p], a1[k], false);
                    a2[k] = __builtin_amdgcn_fdot2(w2u.p[p], dB.p[p], a2[k], false);
                }
            }
        }
        float m0 = a0[0] + bo[0], m1 = a1[0] + bo[1], m2 = a2[0] + bo[2];
        #pragma unroll
        for (int k = 1; k < 9; ++k) {
            m0 = fmaxf(m0, a0[k] + bo[0]);
            m1 = fmaxf(m1, a1[k] + bo[1]);
            m2 = fmaxf(m2, a2[k] + bo[2]);
        }
        mx0[r] = fmaxf(m0, 0.f); mx1[r] = fmaxf(m1, 0.f); mx2[r] = fmaxf(m2, 0.f);
    }
    float* ob = out + ((size_t)b * OC_ + 192) * N_ + n0 + 4 * w;
    *(float4*)&ob[(size_t)(l)       * N_] = make_float4(mx0[0], mx0[1], mx0[2], mx0[3]);
    *(float4*)&ob[(size_t)(l + 64)  * N_] = make_float4(mx1[0], mx1[1], mx1[2], mx1[3]);
    *(float4*)&ob[(size_t)(l + 128) * N_] = make_float4(mx2[0], mx2[1], mx2[2], mx2[3]);
}

extern "C" void kernel_launch(void* const* d_in, const int* in_sizes, int n_in,
                              void* d_out, int out_size, void* d_ws, size_t ws_size,
                              hipStream_t stream) {
    (void)in_sizes; (void)n_in; (void)out_size; (void)ws_size;
    const float* x    = (const float*)d_in[0];
    const float* W    = (const float*)d_in[1];
    const float* bias = (const float*)d_in[2];
    float* out = (float*)d_out;

    _Float16* pHL = (_Float16*)d_ws;                       // 8*3136*384 f16 (hi|lo, node-major)
    float* xT   = (float*)(pHL + (size_t)B_ * N_ * 384);   // 8*3136*192 f32 raw
    float* sq   = xT + (size_t)B_ * N_ * C_;               // 8*3136 f32
    int*   nn   = (int*)(sq + (size_t)B_ * N_);            // 8*3136*9 i32
    float* pkv  = (float*)(nn + (size_t)B_ * N_ * K_);     // partial vals
    int*   pki  = (int*)(pkv + (size_t)B_ * QT_ * MS_ * 64 * 9);

    hipLaunchKernelGGL(prep_k,  dim3(392),  dim3(64),  0, stream, x, pHL, xT, sq);
    hipLaunchKernelGGL(knn_k,   dim3(B_ * QT_ * MS_), dim3(256), 0, stream, pHL, sq, pkv, pki);
    hipLaunchKernelGGL(merge_k, dim3(392),  dim3(64),  0, stream, pkv, pki, nn);
    hipLaunchKernelGGL(convi_k, dim3(784),  dim3(256), 0, stream, x, W, bias, out);
    hipLaunchKernelGGL(convd_k, dim3(1568), dim3(256), 0, stream, xT, nn, W, bias, out);
}